// Round 1
// baseline (829.593 us; speedup 1.0000x reference)
//
#include <hip/hip_runtime.h>
#include <stdint.h>

#define B_    8192
#define N_    40
#define F_    256
#define NBLK_ 4
#define BLK_  10
#define M_    (B_*N_)     /* 327680 rows of A' / blk */
#define NF_   (N_*F_)     /* 10240 features for BN   */

using frag_t = __attribute__((ext_vector_type(8))) short;   // 8 bf16 (4 VGPRs)
using f32x4  = __attribute__((ext_vector_type(4))) float;   // MFMA C/D

__device__ __forceinline__ unsigned short f2b(float x){
  unsigned int u = __float_as_uint(x);
  u += 0x7FFF + ((u >> 16) & 1);          // round-to-nearest-even
  return (unsigned short)(u >> 16);
}
__device__ __forceinline__ float b2f(unsigned short h){
  return __uint_as_float(((unsigned int)h) << 16);
}

// ---------------------------------------------------------------------------
// K0: Wt[f][k] = bf16(W[k][f]) (transposed so MFMA B-fragments are contiguous
//     16B loads), and zero the sum/sumsq accumulators (ws is poisoned 0xAA).
__global__ __launch_bounds__(256) void k_prep(const float* __restrict__ W,
                                              unsigned short* __restrict__ Wt,
                                              float* __restrict__ sums){
  int id = blockIdx.x*256 + threadIdx.x;   // 0..65535
  int f = id >> 8, k = id & 255;
  Wt[f*256 + k] = f2b(W[k*256 + f]);
  if (id < 2*NF_) sums[id] = 0.f;
}

// ---------------------------------------------------------------------------
// K1: A'[b, s+n, :] = sum_j adj[b, s+n, s+j] * input[b, s+j, :]   (bf16 out)
// One workgroup per (b, block). Only the 10x10 diagonal adj blocks are read.
__global__ __launch_bounds__(256) void k_aprime(const float* __restrict__ input,
                                                const float* __restrict__ adj,
                                                unsigned short* __restrict__ A){
  int bb = blockIdx.x; int b = bb >> 2; int s = (bb & 3) * BLK_;
  int f = threadIdx.x;
  __shared__ float sadj[BLK_*BLK_];
  if (f < BLK_*BLK_){
    int n = f / 10, j = f - n*10;
    sadj[f] = adj[b*1600 + (s + n)*40 + (s + j)];
  }
  __syncthreads();
  float acc[BLK_];
  #pragma unroll
  for (int n = 0; n < BLK_; ++n) acc[n] = 0.f;
  const float* ip = input + (size_t)(b*N_ + s)*F_ + f;
  #pragma unroll
  for (int j = 0; j < BLK_; ++j){
    float x = ip[j*F_];                    // coalesced, reused for 10 rows
    #pragma unroll
    for (int n = 0; n < BLK_; ++n) acc[n] += sadj[n*10 + j] * x;
  }
  unsigned short* op = A + (size_t)(b*N_ + s)*F_ + f;
  #pragma unroll
  for (int n = 0; n < BLK_; ++n) op[n*F_] = f2b(acc[n]);
}

// ---------------------------------------------------------------------------
// K2: blk = A' @ W  (bf16 MFMA 16x16x32), IN-PLACE over A' (each workgroup
// owns a 128-row x 256-col stripe; all A reads are staged to LDS before the
// epilogue writes back). B-fragments come straight from L2-resident Wt.
__global__ __launch_bounds__(256, 2) void k_gemm(unsigned short* __restrict__ A,
                                                 const unsigned short* __restrict__ Wt){
  __shared__ unsigned short As[128][136];  // K-half 128 + pad 8 -> 2-way-free banks
  const int t    = threadIdx.x;
  const int m0   = blockIdx.x * 128;
  const int lane = t & 63, wave = t >> 6;
  const int wr   = (wave >> 1) * 64;       // wave row offset (0/64)
  const int wc   = (wave & 1) * 128;       // wave col offset (0/128)
  const int lm   = lane & 15;              // m (A) / n (B) within 16x16 tile
  const int lq   = lane >> 4;              // quad 0..3
  const int lk8  = lq * 8;                 // k offset of this lane's 8 elems

  f32x4 acc[4][8];
  #pragma unroll
  for (int i = 0; i < 4; ++i)
    #pragma unroll
    for (int j = 0; j < 8; ++j)
      acc[i][j] = (f32x4){0.f, 0.f, 0.f, 0.f};

  const unsigned short* Ag = A + (size_t)m0 * 256;
  const int sr = t >> 4, sc = t & 15;      // staging: 16 rows x 16 chunks/iter

  for (int kh = 0; kh < 2; ++kh){          // two K-halves of 128
    __syncthreads();
    #pragma unroll
    for (int it = 0; it < 8; ++it){
      int r = it*16 + sr;
      uint4 v = *(const uint4*)(Ag + r*256 + kh*128 + sc*8);
      *(uint4*)(&As[r][sc*8]) = v;
    }
    __syncthreads();
    #pragma unroll
    for (int kc = 0; kc < 4; ++kc){        // 4 chunks of K=32
      frag_t av[4], bv[8];
      #pragma unroll
      for (int rt = 0; rt < 4; ++rt)
        av[rt] = *(const frag_t*)(&As[wr + rt*16 + lm][kc*32 + lk8]);
      const unsigned short* wp = Wt + (size_t)(wc + lm)*256 + kh*128 + kc*32 + lk8;
      #pragma unroll
      for (int ct = 0; ct < 8; ++ct)
        bv[ct] = *(const frag_t*)(wp + ct*16*256);
      #pragma unroll
      for (int rt = 0; rt < 4; ++rt)
        #pragma unroll
        for (int ct = 0; ct < 8; ++ct)
          acc[rt][ct] = __builtin_amdgcn_mfma_f32_16x16x32_bf16(av[rt], bv[ct], acc[rt][ct], 0, 0, 0);
    }
  }
  // epilogue: C/D layout col=lane&15, row=lq*4+reg  -> write bf16 in-place
  #pragma unroll
  for (int rt = 0; rt < 4; ++rt)
    #pragma unroll
    for (int ct = 0; ct < 8; ++ct){
      int gr = wr + rt*16 + lq*4;
      int gc = wc + ct*16 + lm;
      #pragma unroll
      for (int r = 0; r < 4; ++r)
        A[(size_t)(m0 + gr + r)*256 + gc] = f2b(acc[rt][ct][r]);
    }
}

// ---------------------------------------------------------------------------
// K3: per-feature batch sums. Grid = 40 n-rows x 32 b-slices; thread = f.
__global__ __launch_bounds__(256) void k_stats(const unsigned short* __restrict__ A,
                                               float* __restrict__ sums){
  int n = blockIdx.x % 40, sl = blockIdx.x / 40;
  int f = threadIdx.x;
  float s = 0.f, ss = 0.f;
  int b0 = sl * 256;
  for (int b = b0; b < b0 + 256; ++b){
    float v = b2f(A[(size_t)(b*N_ + n)*256 + f]);
    s += v; ss += v*v;
  }
  atomicAdd(&sums[n*256 + f], s);
  atomicAdd(&sums[NF_ + n*256 + f], ss);
}

// ---------------------------------------------------------------------------
// K3b: per-feature affine. Zero-feature blocks contribute exactly beta, so
// t = sum_i beta[i][nf] - mean*s ; s = gamma[n/10][nf]*rsqrt(var+eps).
__global__ __launch_bounds__(256) void k_finalize(const float* __restrict__ sums,
                                                  const float* __restrict__ gamma,
                                                  const float* __restrict__ beta,
                                                  float* __restrict__ st){
  int nf = blockIdx.x*256 + threadIdx.x;   // 0..10239
  int n = nf >> 8;
  int blki = n / 10;
  float mean = sums[nf] * (1.f/8192.f);
  float var  = sums[NF_ + nf] * (1.f/8192.f) - mean*mean;  // biased var
  float sc = gamma[blki*NF_ + nf] * rsqrtf(var + 1e-5f);
  float tt = -mean * sc;
  #pragma unroll
  for (int i = 0; i < 4; ++i) tt += beta[i*NF_ + nf];
  st[nf] = sc;
  st[NF_ + nf] = tt;
}

// ---------------------------------------------------------------------------
// K4: out[b,n,f] = blk*s[nf] + t[nf]  (fp32 out, 8 elems/thread)
__global__ __launch_bounds__(256) void k_norm(const unsigned short* __restrict__ A,
                                              const float* __restrict__ st,
                                              float* __restrict__ out){
  size_t idx = ((size_t)blockIdx.x*256 + threadIdx.x) * 8;
  uint4 raw = *(const uint4*)(A + idx);
  int nf = (int)(idx % NF_);               // 8-aligned, 10240 % 8 == 0
  const float4 s0 = *(const float4*)(st + nf);
  const float4 s1 = *(const float4*)(st + nf + 4);
  const float4 t0 = *(const float4*)(st + NF_ + nf);
  const float4 t1 = *(const float4*)(st + NF_ + nf + 4);
  float4 o0, o1;
  o0.x = b2f((unsigned short)(raw.x & 0xFFFF)) * s0.x + t0.x;
  o0.y = b2f((unsigned short)(raw.x >> 16))    * s0.y + t0.y;
  o0.z = b2f((unsigned short)(raw.y & 0xFFFF)) * s0.z + t0.z;
  o0.w = b2f((unsigned short)(raw.y >> 16))    * s0.w + t0.w;
  o1.x = b2f((unsigned short)(raw.z & 0xFFFF)) * s1.x + t1.x;
  o1.y = b2f((unsigned short)(raw.z >> 16))    * s1.y + t1.y;
  o1.z = b2f((unsigned short)(raw.w & 0xFFFF)) * s1.z + t1.z;
  o1.w = b2f((unsigned short)(raw.w >> 16))    * s1.w + t1.w;
  *(float4*)(out + idx)     = o0;
  *(float4*)(out + idx + 4) = o1;
}

// ---------------------------------------------------------------------------
extern "C" void kernel_launch(void* const* d_in, const int* in_sizes, int n_in,
                              void* d_out, int out_size, void* d_ws, size_t ws_size,
                              hipStream_t stream){
  const float* input = (const float*)d_in[0];
  const float* adj   = (const float*)d_in[1];
  const float* W     = (const float*)d_in[2];
  const float* gamma = (const float*)d_in[3];
  const float* beta  = (const float*)d_in[4];
  float* out = (float*)d_out;

  char* ws = (char*)d_ws;
  unsigned short* A  = (unsigned short*)ws;                         // M*256 bf16 (A' then blk)
  unsigned short* Wt = (unsigned short*)(ws + (size_t)M_*256*2);    // 256x256 bf16 (transposed)
  float* sums = (float*)(ws + (size_t)M_*256*2 + 256*256*2);        // 2*NF fp32
  float* st   = sums + 2*NF_;                                       // 2*NF fp32 (s, t)

  k_prep    <<<256,        256, 0, stream>>>(W, Wt, sums);
  k_aprime  <<<B_*NBLK_,   256, 0, stream>>>(input, adj, A);
  k_gemm    <<<M_/128,     256, 0, stream>>>(A, Wt);
  k_stats   <<<40*32,      256, 0, stream>>>(A, sums);
  k_finalize<<<NF_/256,    256, 0, stream>>>(sums, gamma, beta, st);
  k_norm    <<<(int)(((size_t)M_*256)/2048), 256, 0, stream>>>(A, st, out);
}